// Round 1
// baseline (115.642 us; speedup 1.0000x reference)
//
#include <hip/hip_runtime.h>
#include <math.h>

// Problem: B=32, C=3, H=W=512, low-pass keeps freqs {-3..2} in both dims (36 coeffs),
// then per-pixel channel MLP 3->8(relu)->3, +lp, clip[0,1].
//
// ws layout (floats):
//   F:    [96][6][6][2]   at 0       (6912 floats)
//   tabc: [6][512]        at 8192    (3072)
//   tabs: [6][512]        at 11264   (3072)
//   G:    [96*512][12]    at 16384   (589824)
// total ~2.43 MB of d_ws.

#define WS_F    0
#define WS_TC   8192
#define WS_TS   11264
#define WS_G    16384

__global__ __launch_bounds__(256) void k_tab(float* __restrict__ ws) {
    int idx = blockIdx.x * 256 + threadIdx.x;
    if (idx >= 6 * 512) return;
    int k = idx >> 9, n = idx & 511;
    const int m[6] = {0, 1, 2, -3, -2, -1};
    double ang = (2.0 * 3.14159265358979323846 * (double)m[k] * (double)n) / 512.0;
    ws[WS_TC + idx] = (float)cos(ang);
    ws[WS_TS + idx] = (float)sin(ang);
}

// Stage A: G[row][kc] = sum_w x[row][w] * exp(-2pi i kc w / 512)
// 4 waves/block, each wave handles 4 rows (16 lanes per row, 32 cols/lane via float4).
__global__ __launch_bounds__(256) void k_fwd_rows(const float* __restrict__ x,
                                                  float* __restrict__ ws) {
    const float* tc = ws + WS_TC;
    const float* tsb = ws + WS_TS;
    float* G = ws + WS_G;
    int t = threadIdx.x;
    int lane = t & 63, wave = t >> 6;
    int sub = lane >> 4;      // which of the wave's 4 rows
    int l16 = lane & 15;
    int row = blockIdx.x * 16 + wave * 4 + sub;   // row = img*512 + h, x addr = row*512
    const float* xr = x + (size_t)row * 512;

    float cr[6] = {0, 0, 0, 0, 0, 0};
    float ci[6] = {0, 0, 0, 0, 0, 0};
#pragma unroll
    for (int j = 0; j < 8; ++j) {
        int w0 = 4 * l16 + 64 * j;
        float4 xv = *(const float4*)(xr + w0);
#pragma unroll
        for (int k = 0; k < 6; ++k) {
            float4 c4 = *(const float4*)(tc + k * 512 + w0);
            float4 s4 = *(const float4*)(tsb + k * 512 + w0);
            cr[k] += xv.x * c4.x + xv.y * c4.y + xv.z * c4.z + xv.w * c4.w;
            ci[k] -= xv.x * s4.x + xv.y * s4.y + xv.z * s4.z + xv.w * s4.w;
        }
    }
    // reduce within each 16-lane group (xor masks 1,2,4,8 stay in-group)
#pragma unroll
    for (int off = 1; off < 16; off <<= 1) {
#pragma unroll
        for (int k = 0; k < 6; ++k) {
            cr[k] += __shfl_xor(cr[k], off, 64);
            ci[k] += __shfl_xor(ci[k], off, 64);
        }
    }
    if (l16 == 0) {
        float* g = G + (size_t)row * 12;   // 48B stride -> 16B aligned
        ((float4*)g)[0] = make_float4(cr[0], ci[0], cr[1], ci[1]);
        ((float4*)g)[1] = make_float4(cr[2], ci[2], cr[3], ci[3]);
        ((float4*)g)[2] = make_float4(cr[4], ci[4], cr[5], ci[5]);
    }
}

// Stage B: F[img][kr][kc] = (1/512^2) sum_h G[img][h][kc] * exp(-2pi i kr h / 512)
__global__ __launch_bounds__(64) void k_fwd_cols(float* __restrict__ ws) {
    const float* tc = ws + WS_TC;
    const float* tsb = ws + WS_TS;
    const float* G = ws + WS_G;
    float* F = ws + WS_F;
    int img = blockIdx.x;
    int lane = threadIdx.x;
    if (lane >= 36) return;
    int kr = lane / 6, kc = lane % 6;
    const float* g = G + (size_t)img * 512 * 12;
    float fre = 0.f, fim = 0.f;
#pragma unroll 8
    for (int h = 0; h < 512; ++h) {
        float gr = g[h * 12 + 2 * kc];
        float gi = g[h * 12 + 2 * kc + 1];
        float c = tc[kr * 512 + h];
        float s = tsb[kr * 512 + h];
        fre += gr * c + gi * s;     // (gr + i gi) * (c - i s)
        fim += gi * c - gr * s;
    }
    const float inv = 1.0f / (512.0f * 512.0f);
    F[img * 72 + lane * 2] = fre * inv;
    F[img * 72 + lane * 2 + 1] = fim * inv;
}

// Output: per (b, 4-row tile): T[c][kc] per row in LDS, then per pixel
// lp = |sum_kc T*e^{+i theta_w}|, MLP 3->8 relu ->3, +lp, clip.
__global__ __launch_bounds__(256) void k_out(const float* __restrict__ ws,
                                             const float* __restrict__ w1,
                                             const float* __restrict__ b1,
                                             const float* __restrict__ w2,
                                             const float* __restrict__ b2,
                                             float* __restrict__ out) {
    const float* tc = ws + WS_TC;
    const float* tsb = ws + WS_TS;
    const float* F = ws + WS_F;
    __shared__ float T[4][3][6][2];
    int t = threadIdx.x;
    int blk = blockIdx.x;
    int b = blk >> 7;                 // 128 blocks per batch element
    int h0 = (blk & 127) << 2;

    if (t < 72) {
        int rl = t / 18, rem = t % 18;
        int c = rem / 6, kc = rem % 6;
        int h = h0 + rl;
        const float* f = F + (b * 3 + c) * 72;
        float tre = 0.f, tim = 0.f;
#pragma unroll
        for (int kr = 0; kr < 6; ++kr) {
            float fr = f[(kr * 6 + kc) * 2];
            float fi = f[(kr * 6 + kc) * 2 + 1];
            float cc = tc[kr * 512 + h];
            float ss = tsb[kr * 512 + h];
            tre += fr * cc - fi * ss;     // (fr + i fi) * (cc + i ss)
            tim += fr * ss + fi * cc;
        }
        T[rl][c][kc][0] = tre;
        T[rl][c][kc][1] = tim;
    }

    // weights into registers (L1-cached broadcasts)
    float rw1[8][3], rb1[8], rw2[3][8], rb2[3];
#pragma unroll
    for (int f_ = 0; f_ < 8; ++f_) {
        rb1[f_] = b1[f_];
#pragma unroll
        for (int c = 0; c < 3; ++c) rw1[f_][c] = w1[f_ * 3 + c];
    }
#pragma unroll
    for (int c = 0; c < 3; ++c) {
        rb2[c] = b2[c];
#pragma unroll
        for (int f_ = 0; f_ < 8; ++f_) rw2[c][f_] = w2[c * 8 + f_];
    }
    __syncthreads();

    int rl = t >> 6, lane = t & 63;
    int h = h0 + rl;
    float Tr[3][6], Ti[3][6];
#pragma unroll
    for (int c = 0; c < 3; ++c)
#pragma unroll
        for (int kc = 0; kc < 6; ++kc) {
            Tr[c][kc] = T[rl][c][kc][0];
            Ti[c][kc] = T[rl][c][kc][1];
        }

#pragma unroll
    for (int j = 0; j < 8; ++j) {
        int w = lane + 64 * j;
        float cw[6], sw[6];
#pragma unroll
        for (int kc = 0; kc < 6; ++kc) {
            cw[kc] = tc[kc * 512 + w];
            sw[kc] = tsb[kc * 512 + w];
        }
        float lp[3];
#pragma unroll
        for (int c = 0; c < 3; ++c) {
            float re = 0.f, im = 0.f;
#pragma unroll
            for (int kc = 0; kc < 6; ++kc) {
                re += Tr[c][kc] * cw[kc] - Ti[c][kc] * sw[kc];
                im += Tr[c][kc] * sw[kc] + Ti[c][kc] * cw[kc];
            }
            lp[c] = sqrtf(re * re + im * im);
        }
        float hid[8];
#pragma unroll
        for (int f_ = 0; f_ < 8; ++f_) {
            float v = rb1[f_] + lp[0] * rw1[f_][0] + lp[1] * rw1[f_][1] + lp[2] * rw1[f_][2];
            hid[f_] = fmaxf(v, 0.0f);
        }
#pragma unroll
        for (int c = 0; c < 3; ++c) {
            float y = rb2[c] + lp[c];
#pragma unroll
            for (int f_ = 0; f_ < 8; ++f_) y += hid[f_] * rw2[c][f_];
            y = fminf(fmaxf(y, 0.0f), 1.0f);
            out[(((size_t)(b * 3 + c) * 512) + h) * 512 + w] = y;
        }
    }
}

extern "C" void kernel_launch(void* const* d_in, const int* in_sizes, int n_in,
                              void* d_out, int out_size, void* d_ws, size_t ws_size,
                              hipStream_t stream) {
    const float* x  = (const float*)d_in[0];
    const float* w1 = (const float*)d_in[1];
    const float* b1 = (const float*)d_in[2];
    const float* w2 = (const float*)d_in[3];
    const float* b2 = (const float*)d_in[4];
    float* out = (float*)d_out;
    float* ws = (float*)d_ws;

    hipLaunchKernelGGL(k_tab, dim3(12), dim3(256), 0, stream, ws);
    hipLaunchKernelGGL(k_fwd_rows, dim3(3072), dim3(256), 0, stream, x, ws);
    hipLaunchKernelGGL(k_fwd_cols, dim3(96), dim3(64), 0, stream, ws);
    hipLaunchKernelGGL(k_out, dim3(4096), dim3(256), 0, stream, ws, w1, b1, w2, b2, out);
}

// Round 2
// 95.398 us; speedup vs baseline: 1.2122x; 1.2122x over previous
//
#include <hip/hip_runtime.h>
#include <math.h>

// B=32, C=3, H=W=512. Low-pass keeps freqs {0,1,2,-3,-2,-1} in both dims.
// Pipeline:
//   k_tab:     twiddle tables (exact integer angle reduction + sincosf)
//   k_colfft:  Gc[img][chunk][k][w] = sum_h x[h][w] e^{-2pi i k h/512}, k=0..3
//              (Hermitian: negative freqs are conjugates)
//   k_combine: sum chunks, then F[img][r][kc] = (1/512^2) sum_w G e^{-2pi i m_kc w/512}
//   k_out:     per row: T[c][kc] = sum_kr F e^{+i kr h}; per pixel synth via
//              register phasor recurrence + |.| + MLP 3->8 relu ->3 + lp, clip.
//
// ws layout (floats): F @0 (6912), tabA @7168 ([512][8]), tabS @11264 ([512][12]),
// P @17408 ([96][nchunk][4][512][2], nchunk chosen from ws_size).

#define WS_F  0
#define WS_TA 7168
#define WS_TS 11264
#define WS_P  17408

__global__ __launch_bounds__(256) void k_tab(float* __restrict__ ws) {
    int h = blockIdx.x * 256 + threadIdx.x;
    if (h >= 512) return;
    const float STEP = 6.28318530717958647692f / 512.0f;
    float* ta = ws + WS_TA + h * 8;
#pragma unroll
    for (int k = 0; k < 4; ++k) {
        int r = (k * h) & 511;            // exact angle reduction
        float s, c;
        sincosf(STEP * (float)r, &s, &c);
        ta[2 * k] = c; ta[2 * k + 1] = s;
    }
    const int mv[6] = {0, 1, 2, -3, -2, -1};
    float* tsp = ws + WS_TS + h * 12;
#pragma unroll
    for (int i = 0; i < 6; ++i) {
        int r = ((mv[i] * h) % 512 + 512) & 511;
        float s, c;
        sincosf(STEP * (float)r, &s, &c);
        tsp[2 * i] = c; tsp[2 * i + 1] = s;
    }
}

// Column transform. Block = (img, h-chunk). 256 threads: halves handle even/odd h,
// each lane owns 4 contiguous w (float4 loads), LDS-combine at the end.
template <int NCHUNK>
__global__ __launch_bounds__(256) void k_colfft(const float* __restrict__ x,
                                                float* __restrict__ ws) {
    constexpr int HSZ = 512 / NCHUNK;
    __shared__ float red[128 * 33];
    const float* tabA = ws + WS_TA;
    float* P = ws + WS_P;
    int img = blockIdx.x / NCHUNK;
    int chunk = blockIdx.x % NCHUNK;
    int t = threadIdx.x;
    int half = t >> 7;
    int tl = t & 127;
    int w0 = tl * 4;
    const float* xb = x + (size_t)img * 262144 + w0;
    int h0 = chunk * HSZ;

    float ar[4][4], ai[4][4];
#pragma unroll
    for (int k = 0; k < 4; ++k)
#pragma unroll
        for (int j = 0; j < 4; ++j) { ar[k][j] = 0.f; ai[k][j] = 0.f; }

#pragma unroll 4
    for (int i = 0; i < HSZ; i += 2) {
        int h = h0 + i + half;
        float4 xv = *(const float4*)(xb + (size_t)h * 512);
        float4 t0 = *(const float4*)(tabA + h * 8);      // wave-uniform
        float4 t1 = *(const float4*)(tabA + h * 8 + 4);
        float c[4] = {t0.x, t0.z, t1.x, t1.z};
        float s[4] = {t0.y, t0.w, t1.y, t1.w};
        float xa[4] = {xv.x, xv.y, xv.z, xv.w};
#pragma unroll
        for (int k = 0; k < 4; ++k)
#pragma unroll
            for (int j = 0; j < 4; ++j) {
                ar[k][j] = fmaf(xa[j], c[k], ar[k][j]);
                ai[k][j] = fmaf(-xa[j], s[k], ai[k][j]);
            }
    }
    if (half == 1) {
        float* r = red + tl * 33;
#pragma unroll
        for (int k = 0; k < 4; ++k)
#pragma unroll
            for (int j = 0; j < 4; ++j) {
                r[k * 8 + j * 2]     = ar[k][j];
                r[k * 8 + j * 2 + 1] = ai[k][j];
            }
    }
    __syncthreads();
    if (half == 0) {
        const float* r = red + tl * 33;
        float* Pb = P + ((size_t)(img * NCHUNK + chunk) * 4) * 1024 + w0 * 2;
#pragma unroll
        for (int k = 0; k < 4; ++k) {
            float4 lo, hi;
            lo.x = ar[k][0] + r[k * 8 + 0];
            lo.y = ai[k][0] + r[k * 8 + 1];
            lo.z = ar[k][1] + r[k * 8 + 2];
            lo.w = ai[k][1] + r[k * 8 + 3];
            hi.x = ar[k][2] + r[k * 8 + 4];
            hi.y = ai[k][2] + r[k * 8 + 5];
            hi.z = ar[k][3] + r[k * 8 + 6];
            hi.w = ai[k][3] + r[k * 8 + 7];
            *(float4*)(Pb + (size_t)k * 1024)     = lo;
            *(float4*)(Pb + (size_t)k * 1024 + 4) = hi;
        }
    }
}

// Sum chunk partials into LDS, then 36 threads compute the 6x6 F block per img.
__global__ __launch_bounds__(256) void k_combine(float* __restrict__ ws, int nchunk) {
    __shared__ float Gs[4096];   // [4][512][2]
    const float* P = ws + WS_P;
    const float* tabS = ws + WS_TS;
    float* F = ws + WS_F;
    int img = blockIdx.x;
    int t = threadIdx.x;
    const float* Pb = P + (size_t)img * nchunk * 4096;
    for (int i = t * 4; i < 4096; i += 1024) {
        float4 acc = make_float4(0.f, 0.f, 0.f, 0.f);
        for (int c = 0; c < nchunk; ++c) {
            float4 v = *(const float4*)(Pb + (size_t)c * 4096 + i);
            acc.x += v.x; acc.y += v.y; acc.z += v.z; acc.w += v.w;
        }
        *(float4*)(Gs + i) = acc;
    }
    __syncthreads();
    if (t < 36) {
        const int kmap[6] = {0, 1, 2, 3, 2, 1};
        const int cnj[6]  = {0, 0, 0, 1, 1, 1};
        int r = t / 6, kc = t % 6;
        int k = kmap[r];
        float sgn = cnj[r] ? -1.f : 1.f;
        float fre = 0.f, fim = 0.f;
        for (int w = 0; w < 512; ++w) {
            float gr = Gs[k * 1024 + w * 2];
            float gi = sgn * Gs[k * 1024 + w * 2 + 1];
            float c = tabS[w * 12 + kc * 2];
            float s = tabS[w * 12 + kc * 2 + 1];
            fre += gr * c + gi * s;       // * e^{-i theta}
            fim += gi * c - gr * s;
        }
        const float inv = 1.0f / (512.0f * 512.0f);
        F[img * 72 + t * 2]     = fre * inv;
        F[img * 72 + t * 2 + 1] = fim * inv;
    }
}

__global__ __launch_bounds__(256) void k_out(const float* __restrict__ ws,
                                             const float* __restrict__ w1,
                                             const float* __restrict__ b1,
                                             const float* __restrict__ w2,
                                             const float* __restrict__ b2,
                                             float* __restrict__ out) {
    const float* tabS = ws + WS_TS;
    const float* F = ws + WS_F;
    __shared__ float T[4][3][12];
    int t = threadIdx.x;
    int blk = blockIdx.x;
    int b = blk >> 7;
    int h0 = (blk & 127) << 2;

    if (t < 72) {
        int rl = t / 18, rem = t % 18;
        int c = rem / 6, kc = rem % 6;
        int h = h0 + rl;
        const float* f = F + (b * 3 + c) * 72;
        const float* th = tabS + h * 12;
        float tre = 0.f, tim = 0.f;
#pragma unroll
        for (int kr = 0; kr < 6; ++kr) {
            float fr = f[(kr * 6 + kc) * 2];
            float fi = f[(kr * 6 + kc) * 2 + 1];
            float cc = th[kr * 2];
            float ss = th[kr * 2 + 1];
            tre += fr * cc - fi * ss;    // * e^{+i theta}
            tim += fr * ss + fi * cc;
        }
        T[rl][c][kc * 2]     = tre;
        T[rl][c][kc * 2 + 1] = tim;
    }

    float rw1[8][3], rb1[8], rw2[3][8], rb2[3];
#pragma unroll
    for (int f_ = 0; f_ < 8; ++f_) {
        rb1[f_] = b1[f_];
#pragma unroll
        for (int c = 0; c < 3; ++c) rw1[f_][c] = w1[f_ * 3 + c];
    }
#pragma unroll
    for (int c = 0; c < 3; ++c) {
        rb2[c] = b2[c];
#pragma unroll
        for (int f_ = 0; f_ < 8; ++f_) rw2[c][f_] = w2[c * 8 + f_];
    }
    __syncthreads();

    int rl = t >> 6, lane = t & 63;
    int h = h0 + rl;
    // fold +/- frequency pairs: S = A0 + U1,V1 (m=+-1) + U2,V2 (m=+-2) + B (m=-3)
    float A0r[3], A0i[3], U1r[3], U1i[3], V1r[3], V1i[3];
    float U2r[3], U2i[3], V2r[3], V2i[3], Br[3], Bi[3];
#pragma unroll
    for (int c = 0; c < 3; ++c) {
        const float* Tc = T[rl][c];
        A0r[c] = Tc[0];  A0i[c] = Tc[1];
        float t1r = Tc[2],  t1i = Tc[3];    // m=+1
        float t2r = Tc[4],  t2i = Tc[5];    // m=+2
        float bmr = Tc[6],  bmi = Tc[7];    // m=-3
        float m2r = Tc[8],  m2i = Tc[9];    // m=-2
        float m1r = Tc[10], m1i = Tc[11];   // m=-1
        U1r[c] = t1r + m1r; U1i[c] = t1i + m1i;
        V1r[c] = t1r - m1r; V1i[c] = t1i - m1i;
        U2r[c] = t2r + m2r; U2i[c] = t2i + m2i;
        V2r[c] = t2r - m2r; V2i[c] = t2i - m2i;
        Br[c] = bmr; Bi[c] = bmi;
    }
    // phasors e^{+2pi i p w/512}, p=1,2,3, init at w=lane from table
    const float* tw = tabS + lane * 12;
    float c1 = tw[2], s1 = tw[3];
    float c2 = tw[4], s2 = tw[5];
    float c3 = tw[6], s3 = -tw[7];          // entry 3 stores m=-3
    const float K = 0.70710678118654752440f;
    float* ob = out + ((size_t)(b * 3) * 512 + h) * 512;

#pragma unroll
    for (int j = 0; j < 8; ++j) {
        int w = lane + 64 * j;
        float lp[3];
#pragma unroll
        for (int c = 0; c < 3; ++c) {
            float re = A0r[c] + U1r[c] * c1 - V1i[c] * s1
                              + U2r[c] * c2 - V2i[c] * s2
                              + Br[c] * c3 + Bi[c] * s3;
            float im = A0i[c] + U1i[c] * c1 + V1r[c] * s1
                              + U2i[c] * c2 + V2r[c] * s2
                              + Bi[c] * c3 - Br[c] * s3;
            lp[c] = sqrtf(re * re + im * im);
        }
        float hid[8];
#pragma unroll
        for (int f_ = 0; f_ < 8; ++f_) {
            float v = rb1[f_] + lp[0] * rw1[f_][0] + lp[1] * rw1[f_][1] + lp[2] * rw1[f_][2];
            hid[f_] = fmaxf(v, 0.0f);
        }
#pragma unroll
        for (int c = 0; c < 3; ++c) {
            float y = rb2[c] + lp[c];
#pragma unroll
            for (int f_ = 0; f_ < 8; ++f_) y += hid[f_] * rw2[c][f_];
            y = fminf(fmaxf(y, 0.0f), 1.0f);
            ob[(size_t)c * 262144 + w] = y;
        }
        if (j < 7) {  // advance phasors by e^{+i pi p/4}
            float nc1 = K * (c1 - s1), ns1 = K * (c1 + s1);
            float nc2 = -s2,           ns2 = c2;
            float nc3 = -K * (c3 + s3), ns3 = K * (c3 - s3);
            c1 = nc1; s1 = ns1; c2 = nc2; s2 = ns2; c3 = nc3; s3 = ns3;
        }
    }
}

extern "C" void kernel_launch(void* const* d_in, const int* in_sizes, int n_in,
                              void* d_out, int out_size, void* d_ws, size_t ws_size,
                              hipStream_t stream) {
    const float* x  = (const float*)d_in[0];
    const float* w1 = (const float*)d_in[1];
    const float* b1 = (const float*)d_in[2];
    const float* w2 = (const float*)d_in[3];
    const float* b2 = (const float*)d_in[4];
    float* out = (float*)d_out;
    float* ws = (float*)d_ws;

    size_t wsf = ws_size / 4;
    size_t avail = (wsf > WS_P) ? (wsf - WS_P) : 0;
    int nchunk = 1;
    if (avail >= (size_t)8 * 393216) nchunk = 8;
    else if (avail >= (size_t)4 * 393216) nchunk = 4;
    else if (avail >= (size_t)2 * 393216) nchunk = 2;

    hipLaunchKernelGGL(k_tab, dim3(2), dim3(256), 0, stream, ws);
    switch (nchunk) {
        case 8: hipLaunchKernelGGL((k_colfft<8>), dim3(96 * 8), dim3(256), 0, stream, x, ws); break;
        case 4: hipLaunchKernelGGL((k_colfft<4>), dim3(96 * 4), dim3(256), 0, stream, x, ws); break;
        case 2: hipLaunchKernelGGL((k_colfft<2>), dim3(96 * 2), dim3(256), 0, stream, x, ws); break;
        default: hipLaunchKernelGGL((k_colfft<1>), dim3(96), dim3(256), 0, stream, x, ws); break;
    }
    hipLaunchKernelGGL(k_combine, dim3(96), dim3(256), 0, stream, ws, nchunk);
    hipLaunchKernelGGL(k_out, dim3(4096), dim3(256), 0, stream, ws, w1, b1, w2, b2, out);
}

// Round 3
// 88.402 us; speedup vs baseline: 1.3081x; 1.0791x over previous
//
#include <hip/hip_runtime.h>
#include <math.h>

// B=32, C=3, H=W=512. Low-pass keeps freqs {0,1,2,-3,-2,-1} in both dims.
// Pipeline (3 kernels):
//   k_tab:    twiddle tables (exact integer angle reduction + sincosf)
//   k_colfft: per (img, h-chunk): A[k][w] = sum_h x[h][w] e^{-2pi i k h/512} (k=0..3)
//             staged in LDS, then projected onto col freqs m=-3..3:
//             P[img][chunk][k][m] = sum_w A[k][w] e^{-2pi i m w/512}   (56 floats/block)
//   k_out:    72 threads sum chunk partials -> F (Hermitian-expanded rows), per-row
//             T[c][kc]; per pixel synth via register phasor recurrence, |.|,
//             MLP 3->8 relu ->3, +lp, clip.
//
// ws layout (floats): tabA @0 ([512][8]), tabS @4096 ([512][12]),
//                     P @10240 ([96][8][28][2])  -- ~208 KB total.

#define WS_TA 0
#define WS_TS 4096
#define WS_P  10240
constexpr int NCHUNK = 8;

__global__ __launch_bounds__(256) void k_tab(float* __restrict__ ws) {
    int h = blockIdx.x * 256 + threadIdx.x;
    if (h >= 512) return;
    const float STEP = 6.28318530717958647692f / 512.0f;
    float* ta = ws + WS_TA + h * 8;
#pragma unroll
    for (int k = 0; k < 4; ++k) {
        int r = (k * h) & 511;            // exact angle reduction
        float s, c;
        sincosf(STEP * (float)r, &s, &c);
        ta[2 * k] = c; ta[2 * k + 1] = s;
    }
    const int mv[6] = {0, 1, 2, -3, -2, -1};
    float* tsp = ws + WS_TS + h * 12;
#pragma unroll
    for (int i = 0; i < 6; ++i) {
        int r = ((mv[i] * h) % 512 + 512) & 511;
        float s, c;
        sincosf(STEP * (float)r, &s, &c);
        tsp[2 * i] = c; tsp[2 * i + 1] = s;
    }
}

// Block = (img, h-chunk of 64 rows). 256 threads: halves handle even/odd h,
// each lane owns 4 contiguous w (float4 loads). Epilogue: LDS-combine halves,
// project onto 7 column freqs, write 56-float partial.
__global__ __launch_bounds__(256) void k_colfft(const float* __restrict__ x,
                                                float* __restrict__ ws) {
    constexpr int HSZ = 512 / NCHUNK;   // 64
    __shared__ float As[4][2][512];     // planar [k][re/im][w], 16 KB
    __shared__ float Rs[28][8][2];
    const float* tabA = ws + WS_TA;
    const float* tabS = ws + WS_TS;
    float* P = ws + WS_P;
    int img = blockIdx.x / NCHUNK;
    int chunk = blockIdx.x % NCHUNK;
    int t = threadIdx.x;
    int half = t >> 7;
    int tl = t & 127;
    int w0 = tl * 4;
    const float* xb = x + (size_t)img * 262144 + w0;
    int h0 = chunk * HSZ;

    float ar[4][4], ai[4][4];
#pragma unroll
    for (int k = 0; k < 4; ++k)
#pragma unroll
        for (int j = 0; j < 4; ++j) { ar[k][j] = 0.f; ai[k][j] = 0.f; }

#pragma unroll 4
    for (int i = 0; i < HSZ; i += 2) {
        int h = h0 + i + half;
        float4 xv = *(const float4*)(xb + (size_t)h * 512);
        float4 t0 = *(const float4*)(tabA + h * 8);      // wave-uniform
        float4 t1 = *(const float4*)(tabA + h * 8 + 4);
        float c[4] = {t0.x, t0.z, t1.x, t1.z};
        float s[4] = {t0.y, t0.w, t1.y, t1.w};
        float xa[4] = {xv.x, xv.y, xv.z, xv.w};
#pragma unroll
        for (int k = 0; k < 4; ++k)
#pragma unroll
            for (int j = 0; j < 4; ++j) {
                ar[k][j] = fmaf(xa[j], c[k], ar[k][j]);
                ai[k][j] = fmaf(-xa[j], s[k], ai[k][j]);
            }
    }

    if (half == 1) {
#pragma unroll
        for (int k = 0; k < 4; ++k) {
            *(float4*)&As[k][0][w0] = make_float4(ar[k][0], ar[k][1], ar[k][2], ar[k][3]);
            *(float4*)&As[k][1][w0] = make_float4(ai[k][0], ai[k][1], ai[k][2], ai[k][3]);
        }
    }
    __syncthreads();
    if (half == 0) {
#pragma unroll
        for (int k = 0; k < 4; ++k) {
            float4 vr = *(const float4*)&As[k][0][w0];
            float4 vi = *(const float4*)&As[k][1][w0];
            vr.x += ar[k][0]; vr.y += ar[k][1]; vr.z += ar[k][2]; vr.w += ar[k][3];
            vi.x += ai[k][0]; vi.y += ai[k][1]; vi.z += ai[k][2]; vi.w += ai[k][3];
            *(float4*)&As[k][0][w0] = vr;
            *(float4*)&As[k][1][w0] = vi;
        }
    }
    __syncthreads();

    // projection: 224 threads = (k:4, mi:7, seg:8); m_val = mi-3
    if (t < 224) {
        int pair = t >> 3;            // k*7 + mi
        int seg = t & 7;
        int k = pair / 7, mi = pair % 7;
        int entry = (mi < 3) ? mi + 3 : (mi < 6 ? mi - 3 : 3);
        float sigma = (mi == 6) ? -1.f : 1.f;
        int rot = (8 * seg + 2 * k) & 63;   // bank stagger
        float pre = 0.f, pim = 0.f;
        const float* A0 = &As[k][0][0];
        const float* A1 = &As[k][1][0];
#pragma unroll 4
        for (int i = 0; i < 64; ++i) {
            int w = seg * 64 + ((i + rot) & 63);
            float Are = A0[w], Aim = A1[w];
            float c = tabS[w * 12 + entry * 2];
            float s = sigma * tabS[w * 12 + entry * 2 + 1];
            pre += Are * c + Aim * s;    // * e^{-i m w theta}
            pim += Aim * c - Are * s;
        }
        Rs[pair][seg][0] = pre;
        Rs[pair][seg][1] = pim;
    }
    __syncthreads();
    if (t < 56) {
        int pair = t >> 1, part = t & 1;
        float sum = 0.f;
#pragma unroll
        for (int g = 0; g < 8; ++g) sum += Rs[pair][g][part];
        P[((size_t)(img * NCHUNK + chunk) * 28 + pair) * 2 + part] = sum;
    }
}

__global__ __launch_bounds__(256) void k_out(const float* __restrict__ ws,
                                             const float* __restrict__ w1,
                                             const float* __restrict__ b1,
                                             const float* __restrict__ w2,
                                             const float* __restrict__ b2,
                                             float* __restrict__ out) {
    const float* tabS = ws + WS_TS;
    const float* P = ws + WS_P;
    __shared__ float T[4][3][12];
    int t = threadIdx.x;
    int blk = blockIdx.x;
    int b = blk >> 7;
    int h0 = (blk & 127) << 2;

    if (t < 72) {
        int rl = t / 18, rem = t % 18;
        int c = rem / 6, kc = rem % 6;
        int h = h0 + rl;
        const float* Pc = P + (size_t)((b * 3 + c) * NCHUNK) * 56;
        const float* th = tabS + h * 12;
        int m_kc = (kc < 3) ? kc : kc - 6;
        const float inv = 1.0f / (512.0f * 512.0f);
        float tre = 0.f, tim = 0.f;
#pragma unroll
        for (int kr = 0; kr < 6; ++kr) {
            int kk, mi; float csign;
            if (kr < 3) { kk = kr;     mi = m_kc + 3; csign =  1.f; }
            else        { kk = 6 - kr; mi = 3 - m_kc; csign = -1.f; }
            int pair = kk * 7 + mi;
            float fr = 0.f, fi = 0.f;
#pragma unroll
            for (int ch = 0; ch < NCHUNK; ++ch) {
                const float* pp = Pc + (ch * 28 + pair) * 2;
                fr += pp[0]; fi += pp[1];
            }
            fr *= inv; fi *= csign * inv;
            float cc = th[kr * 2], ss = th[kr * 2 + 1];
            tre += fr * cc - fi * ss;    // * e^{+i m_r h theta}
            tim += fr * ss + fi * cc;
        }
        T[rl][c][kc * 2]     = tre;
        T[rl][c][kc * 2 + 1] = tim;
    }

    float rw1[8][3], rb1[8], rw2[3][8], rb2[3];
#pragma unroll
    for (int f_ = 0; f_ < 8; ++f_) {
        rb1[f_] = b1[f_];
#pragma unroll
        for (int c = 0; c < 3; ++c) rw1[f_][c] = w1[f_ * 3 + c];
    }
#pragma unroll
    for (int c = 0; c < 3; ++c) {
        rb2[c] = b2[c];
#pragma unroll
        for (int f_ = 0; f_ < 8; ++f_) rw2[c][f_] = w2[c * 8 + f_];
    }
    __syncthreads();

    int rl = t >> 6, lane = t & 63;
    int h = h0 + rl;
    // fold +/- frequency pairs: S = A0 + (U1,V1) e1 + (U2,V2) e2 + B e{-3}
    float A0r[3], A0i[3], U1r[3], U1i[3], V1r[3], V1i[3];
    float U2r[3], U2i[3], V2r[3], V2i[3], Br[3], Bi[3];
#pragma unroll
    for (int c = 0; c < 3; ++c) {
        const float* Tc = T[rl][c];
        A0r[c] = Tc[0];  A0i[c] = Tc[1];
        float t1r = Tc[2],  t1i = Tc[3];    // m=+1
        float t2r = Tc[4],  t2i = Tc[5];    // m=+2
        float bmr = Tc[6],  bmi = Tc[7];    // m=-3
        float m2r = Tc[8],  m2i = Tc[9];    // m=-2
        float m1r = Tc[10], m1i = Tc[11];   // m=-1
        U1r[c] = t1r + m1r; U1i[c] = t1i + m1i;
        V1r[c] = t1r - m1r; V1i[c] = t1i - m1i;
        U2r[c] = t2r + m2r; U2i[c] = t2i + m2i;
        V2r[c] = t2r - m2r; V2i[c] = t2i - m2i;
        Br[c] = bmr; Bi[c] = bmi;
    }
    // phasors e^{+2pi i p w/512}, p=1,2,3, init at w=lane from table
    const float* tw = tabS + lane * 12;
    float c1 = tw[2], s1 = tw[3];
    float c2 = tw[4], s2 = tw[5];
    float c3 = tw[6], s3 = -tw[7];          // entry 3 stores m=-3
    const float K = 0.70710678118654752440f;
    float* ob = out + ((size_t)(b * 3) * 512 + h) * 512;

#pragma unroll
    for (int j = 0; j < 8; ++j) {
        int w = lane + 64 * j;
        float lp[3];
#pragma unroll
        for (int c = 0; c < 3; ++c) {
            float re = A0r[c] + U1r[c] * c1 - V1i[c] * s1
                              + U2r[c] * c2 - V2i[c] * s2
                              + Br[c] * c3 + Bi[c] * s3;
            float im = A0i[c] + U1i[c] * c1 + V1r[c] * s1
                              + U2i[c] * c2 + V2r[c] * s2
                              + Bi[c] * c3 - Br[c] * s3;
            lp[c] = sqrtf(re * re + im * im);
        }
        float hid[8];
#pragma unroll
        for (int f_ = 0; f_ < 8; ++f_) {
            float v = rb1[f_] + lp[0] * rw1[f_][0] + lp[1] * rw1[f_][1] + lp[2] * rw1[f_][2];
            hid[f_] = fmaxf(v, 0.0f);
        }
#pragma unroll
        for (int c = 0; c < 3; ++c) {
            float y = rb2[c] + lp[c];
#pragma unroll
            for (int f_ = 0; f_ < 8; ++f_) y += hid[f_] * rw2[c][f_];
            y = fminf(fmaxf(y, 0.0f), 1.0f);
            ob[(size_t)c * 262144 + w] = y;
        }
        if (j < 7) {  // advance phasors by e^{+i pi p/4}
            float nc1 = K * (c1 - s1), ns1 = K * (c1 + s1);
            float nc2 = -s2,           ns2 = c2;
            float nc3 = -K * (c3 + s3), ns3 = K * (c3 - s3);
            c1 = nc1; s1 = ns1; c2 = nc2; s2 = ns2; c3 = nc3; s3 = ns3;
        }
    }
}

extern "C" void kernel_launch(void* const* d_in, const int* in_sizes, int n_in,
                              void* d_out, int out_size, void* d_ws, size_t ws_size,
                              hipStream_t stream) {
    const float* x  = (const float*)d_in[0];
    const float* w1 = (const float*)d_in[1];
    const float* b1 = (const float*)d_in[2];
    const float* w2 = (const float*)d_in[3];
    const float* b2 = (const float*)d_in[4];
    float* out = (float*)d_out;
    float* ws = (float*)d_ws;

    hipLaunchKernelGGL(k_tab, dim3(2), dim3(256), 0, stream, ws);
    hipLaunchKernelGGL(k_colfft, dim3(96 * NCHUNK), dim3(256), 0, stream, x, ws);
    hipLaunchKernelGGL(k_out, dim3(4096), dim3(256), 0, stream, ws, w1, b1, w2, b2, out);
}

// Round 4
// 76.931 us; speedup vs baseline: 1.5032x; 1.1491x over previous
//
#include <hip/hip_runtime.h>
#include <math.h>

// B=32, C=3, H=W=512. Low-pass keeps freqs {0,1,2,-3,-2,-1} in both dims.
// Pipeline (3 kernels):
//   k_tab:    twiddle tables (exact integer angle reduction + sincosf)
//   k_colfft: per (img, 32-row chunk): A[k][w] = sum_h x[h][w] e^{-2pi i k h/512}
//             (k=0..3) staged in LDS (segment-major, bank-padded), then projected
//             onto col freqs m=-3..3 via per-thread phasor recurrence:
//             P[img][chunk][k][m]  (56 floats/block)
//   k_out:    72 threads sum chunk partials -> T[c][kc] per row; per pixel synth
//             via register phasor recurrence, |.|, MLP 3->8 relu ->3, +lp, clip.
//
// ws layout (floats): tabA @0 ([512][8]), tabS @4096 ([512][12]),
//                     P @10240 ([96][16][28][2]) -- ~376 KB total.

#define WS_TA 0
#define WS_TS 4096
#define WS_P  10240
constexpr int NCHUNK = 16;
constexpr int HSZ = 512 / NCHUNK;   // 32

__global__ __launch_bounds__(256) void k_tab(float* __restrict__ ws) {
    int h = blockIdx.x * 256 + threadIdx.x;
    if (h >= 512) return;
    const float STEP = 6.28318530717958647692f / 512.0f;
    float* ta = ws + WS_TA + h * 8;
#pragma unroll
    for (int k = 0; k < 4; ++k) {
        int r = (k * h) & 511;            // exact angle reduction
        float s, c;
        sincosf(STEP * (float)r, &s, &c);
        ta[2 * k] = c; ta[2 * k + 1] = s;
    }
    const int mv[6] = {0, 1, 2, -3, -2, -1};
    float* tsp = ws + WS_TS + h * 12;
#pragma unroll
    for (int i = 0; i < 6; ++i) {
        int r = ((mv[i] * h) % 512 + 512) & 511;
        float s, c;
        sincosf(STEP * (float)r, &s, &c);
        tsp[2 * i] = c; tsp[2 * i + 1] = s;
    }
}

// Block = (img, 32-row chunk). 256 threads: halves handle even/odd rows, each
// lane owns 4 contiguous w. Twiddles staged in LDS. Epilogue: combine halves
// into As[k][p][seg][72] (bank-staggered), project 7 col freqs by recurrence.
__global__ __launch_bounds__(256, 6) void k_colfft(const float* __restrict__ x,
                                                   float* __restrict__ ws) {
    __shared__ float As[4][2][8][72];   // [k][re/im][w-seg][j + pad] ~18.4 KB
    __shared__ float Ts[HSZ][8];        // tabA rows for this chunk
    __shared__ float Rs[28][8][2];
    float* P = ws + WS_P;
    int img = blockIdx.x / NCHUNK;
    int chunk = blockIdx.x % NCHUNK;
    int t = threadIdx.x;
    int half = t >> 7;
    int tl = t & 127;
    int w0 = tl * 4;
    int wseg = tl >> 4;            // w0 >> 6
    int wj = (tl & 15) * 4;        // w0 & 63
    int h0 = chunk * HSZ;

    Ts[t >> 3][t & 7] = ws[WS_TA + (h0 + (t >> 3)) * 8 + (t & 7)];
    __syncthreads();

    const float* xb = x + (size_t)img * 262144 + w0;
    float ar[4][4], ai[4][4];
#pragma unroll
    for (int k = 0; k < 4; ++k)
#pragma unroll
        for (int j = 0; j < 4; ++j) { ar[k][j] = 0.f; ai[k][j] = 0.f; }

#pragma unroll 2
    for (int i = 0; i < HSZ; i += 4) {
        int la = i + half, lb = i + 2 + half;          // local rows
        float4 xva = *(const float4*)(xb + (size_t)(h0 + la) * 512);
        float4 xvb = *(const float4*)(xb + (size_t)(h0 + lb) * 512);
        float4 ta0 = *(const float4*)&Ts[la][0];
        float4 ta1 = *(const float4*)&Ts[la][4];
        float4 tb0 = *(const float4*)&Ts[lb][0];
        float4 tb1 = *(const float4*)&Ts[lb][4];
        float ca[4] = {ta0.x, ta0.z, ta1.x, ta1.z};
        float sa[4] = {ta0.y, ta0.w, ta1.y, ta1.w};
        float cb[4] = {tb0.x, tb0.z, tb1.x, tb1.z};
        float sb[4] = {tb0.y, tb0.w, tb1.y, tb1.w};
        float xaa[4] = {xva.x, xva.y, xva.z, xva.w};
        float xbb[4] = {xvb.x, xvb.y, xvb.z, xvb.w};
#pragma unroll
        for (int k = 0; k < 4; ++k)
#pragma unroll
            for (int j = 0; j < 4; ++j) {
                ar[k][j] = fmaf(xaa[j], ca[k], ar[k][j]);
                ai[k][j] = fmaf(-xaa[j], sa[k], ai[k][j]);
                ar[k][j] = fmaf(xbb[j], cb[k], ar[k][j]);
                ai[k][j] = fmaf(-xbb[j], sb[k], ai[k][j]);
            }
    }

    if (half == 1) {
#pragma unroll
        for (int k = 0; k < 4; ++k) {
            *(float4*)&As[k][0][wseg][wj] = make_float4(ar[k][0], ar[k][1], ar[k][2], ar[k][3]);
            *(float4*)&As[k][1][wseg][wj] = make_float4(ai[k][0], ai[k][1], ai[k][2], ai[k][3]);
        }
    }
    __syncthreads();
    if (half == 0) {
#pragma unroll
        for (int k = 0; k < 4; ++k) {
            float4 vr = *(const float4*)&As[k][0][wseg][wj];
            float4 vi = *(const float4*)&As[k][1][wseg][wj];
            vr.x += ar[k][0]; vr.y += ar[k][1]; vr.z += ar[k][2]; vr.w += ar[k][3];
            vi.x += ai[k][0]; vi.y += ai[k][1]; vi.z += ai[k][2]; vi.w += ai[k][3];
            *(float4*)&As[k][0][wseg][wj] = vr;
            *(float4*)&As[k][1][wseg][wj] = vi;
        }
    }
    __syncthreads();

    // projection: 224 threads = (pair = k*7+mi, seg); m = mi-3; phasor recurrence
    if (t < 224) {
        int pair = t >> 3;
        int seg = t & 7;
        int k = pair / 7, mi = pair % 7;
        float m = (float)(mi - 3);
        const float TH = 6.28318530717958647692f / 512.0f;
        float pc, ps, cm, sm;
        sincosf(-m * (float)seg * 0.78539816339744830962f, &ps, &pc);  // -m*seg*pi/4
        sincosf(-m * TH, &sm, &cm);
        const float* A0 = &As[k][0][seg][0];
        const float* A1 = &As[k][1][seg][0];
        float pre = 0.f, pim = 0.f;
#pragma unroll 4
        for (int j = 0; j < 64; ++j) {
            float Ar = A0[j], Ai = A1[j];
            pre += Ar * pc - Ai * ps;     // A * (pc + i ps), ph = e^{-i m w th}
            pim += Ar * ps + Ai * pc;
            float npc = pc * cm - ps * sm;
            float nps = ps * cm + pc * sm;
            pc = npc; ps = nps;
        }
        Rs[pair][seg][0] = pre;
        Rs[pair][seg][1] = pim;
    }
    __syncthreads();
    if (t < 56) {
        int pair = t >> 1, part = t & 1;
        float sum = 0.f;
#pragma unroll
        for (int g = 0; g < 8; ++g) sum += Rs[pair][g][part];
        P[((size_t)(img * NCHUNK + chunk) * 28 + pair) * 2 + part] = sum;
    }
}

__global__ __launch_bounds__(256) void k_out(const float* __restrict__ ws,
                                             const float* __restrict__ w1,
                                             const float* __restrict__ b1,
                                             const float* __restrict__ w2,
                                             const float* __restrict__ b2,
                                             float* __restrict__ out) {
    const float* tabS = ws + WS_TS;
    const float* P = ws + WS_P;
    __shared__ float T[4][3][12];
    int t = threadIdx.x;
    int blk = blockIdx.x;
    int b = blk >> 7;
    int h0 = (blk & 127) << 2;

    if (t < 72) {
        int rl = t / 18, rem = t % 18;
        int c = rem / 6, kc = rem % 6;
        int h = h0 + rl;
        const float* Pc = P + (size_t)((b * 3 + c) * NCHUNK) * 56;
        const float* th = tabS + h * 12;
        int m_kc = (kc < 3) ? kc : kc - 6;
        const float inv = 1.0f / (512.0f * 512.0f);
        float tre = 0.f, tim = 0.f;
#pragma unroll
        for (int kr = 0; kr < 6; ++kr) {
            int kk, mi; float csign;
            if (kr < 3) { kk = kr;     mi = m_kc + 3; csign =  1.f; }
            else        { kk = 6 - kr; mi = 3 - m_kc; csign = -1.f; }
            int pair = kk * 7 + mi;
            float fr = 0.f, fi = 0.f;
#pragma unroll
            for (int ch = 0; ch < NCHUNK; ++ch) {
                const float* pp = Pc + (ch * 28 + pair) * 2;
                fr += pp[0]; fi += pp[1];
            }
            fr *= inv; fi *= csign * inv;
            float cc = th[kr * 2], ss = th[kr * 2 + 1];
            tre += fr * cc - fi * ss;    // * e^{+i m_r h theta}
            tim += fr * ss + fi * cc;
        }
        T[rl][c][kc * 2]     = tre;
        T[rl][c][kc * 2 + 1] = tim;
    }

    float rw1[8][3], rb1[8], rw2[3][8], rb2[3];
#pragma unroll
    for (int f_ = 0; f_ < 8; ++f_) {
        rb1[f_] = b1[f_];
#pragma unroll
        for (int c = 0; c < 3; ++c) rw1[f_][c] = w1[f_ * 3 + c];
    }
#pragma unroll
    for (int c = 0; c < 3; ++c) {
        rb2[c] = b2[c];
#pragma unroll
        for (int f_ = 0; f_ < 8; ++f_) rw2[c][f_] = w2[c * 8 + f_];
    }
    __syncthreads();

    int rl = t >> 6, lane = t & 63;
    int h = h0 + rl;
    // fold +/- frequency pairs: S = A0 + (U1,V1) e1 + (U2,V2) e2 + B e{-3}
    float A0r[3], A0i[3], U1r[3], U1i[3], V1r[3], V1i[3];
    float U2r[3], U2i[3], V2r[3], V2i[3], Br[3], Bi[3];
#pragma unroll
    for (int c = 0; c < 3; ++c) {
        const float* Tc = T[rl][c];
        A0r[c] = Tc[0];  A0i[c] = Tc[1];
        float t1r = Tc[2],  t1i = Tc[3];    // m=+1
        float t2r = Tc[4],  t2i = Tc[5];    // m=+2
        float bmr = Tc[6],  bmi = Tc[7];    // m=-3
        float m2r = Tc[8],  m2i = Tc[9];    // m=-2
        float m1r = Tc[10], m1i = Tc[11];   // m=-1
        U1r[c] = t1r + m1r; U1i[c] = t1i + m1i;
        V1r[c] = t1r - m1r; V1i[c] = t1i - m1i;
        U2r[c] = t2r + m2r; U2i[c] = t2i + m2i;
        V2r[c] = t2r - m2r; V2i[c] = t2i - m2i;
        Br[c] = bmr; Bi[c] = bmi;
    }
    // phasors e^{+2pi i p w/512}, p=1,2,3, init at w=lane from table
    const float* tw = tabS + lane * 12;
    float c1 = tw[2], s1 = tw[3];
    float c2 = tw[4], s2 = tw[5];
    float c3 = tw[6], s3 = -tw[7];          // entry 3 stores m=-3
    const float K = 0.70710678118654752440f;
    float* ob = out + ((size_t)(b * 3) * 512 + h) * 512;

#pragma unroll
    for (int j = 0; j < 8; ++j) {
        int w = lane + 64 * j;
        float lp[3];
#pragma unroll
        for (int c = 0; c < 3; ++c) {
            float re = A0r[c] + U1r[c] * c1 - V1i[c] * s1
                              + U2r[c] * c2 - V2i[c] * s2
                              + Br[c] * c3 + Bi[c] * s3;
            float im = A0i[c] + U1i[c] * c1 + V1r[c] * s1
                              + U2i[c] * c2 + V2r[c] * s2
                              + Bi[c] * c3 - Br[c] * s3;
            lp[c] = sqrtf(re * re + im * im);
        }
        float hid[8];
#pragma unroll
        for (int f_ = 0; f_ < 8; ++f_) {
            float v = rb1[f_] + lp[0] * rw1[f_][0] + lp[1] * rw1[f_][1] + lp[2] * rw1[f_][2];
            hid[f_] = fmaxf(v, 0.0f);
        }
#pragma unroll
        for (int c = 0; c < 3; ++c) {
            float y = rb2[c] + lp[c];
#pragma unroll
            for (int f_ = 0; f_ < 8; ++f_) y += hid[f_] * rw2[c][f_];
            y = fminf(fmaxf(y, 0.0f), 1.0f);
            ob[(size_t)c * 262144 + w] = y;
        }
        if (j < 7) {  // advance phasors by e^{+i pi p/4}
            float nc1 = K * (c1 - s1), ns1 = K * (c1 + s1);
            float nc2 = -s2,           ns2 = c2;
            float nc3 = -K * (c3 + s3), ns3 = K * (c3 - s3);
            c1 = nc1; s1 = ns1; c2 = nc2; s2 = ns2; c3 = nc3; s3 = ns3;
        }
    }
}

extern "C" void kernel_launch(void* const* d_in, const int* in_sizes, int n_in,
                              void* d_out, int out_size, void* d_ws, size_t ws_size,
                              hipStream_t stream) {
    const float* x  = (const float*)d_in[0];
    const float* w1 = (const float*)d_in[1];
    const float* b1 = (const float*)d_in[2];
    const float* w2 = (const float*)d_in[3];
    const float* b2 = (const float*)d_in[4];
    float* out = (float*)d_out;
    float* ws = (float*)d_ws;

    hipLaunchKernelGGL(k_tab, dim3(2), dim3(256), 0, stream, ws);
    hipLaunchKernelGGL(k_colfft, dim3(96 * NCHUNK), dim3(256), 0, stream, x, ws);
    hipLaunchKernelGGL(k_out, dim3(4096), dim3(256), 0, stream, ws, w1, b1, w2, b2, out);
}